// Round 1
// baseline (273.612 us; speedup 1.0000x reference)
//
#include <hip/hip_runtime.h>

// AttentionModule: 3-layer sigmoid-QKV attention, B=64 N=1024 R=128 D=64 H=64.
// R12: in-register-softmax flash loop. R11 (268us) was barrier-serialized:
// MfmaUtil 23.5% matched exactly 41K MFMA-cycles / 171K total; 3 barriers/iter
// lock-stepped QK -> P_lds -> PV across waves. R12 restructure:
//  - each wave owns 32 q rows; swapped QK (mfma(K,Q)) puts P rows lane-local
//  - P (and Q) fragments built in-register via v_cvt_pk_bf16_f32 +
//    v_permlane32_swap_b32 (T12): no P_lds, no Q_lds
//  - K/V double-buffered in LDS (71680 B, 2 blocks/CU unchanged):
//    ONE __syncthreads per KV tile (16 vs 48 in the loop)
//  - rowsum wave-private -> epilogue D/E barriers dropped
// Pipeline unchanged: prep, xk0 (xpose+K0/V0), flash0(+K1/V1), flash1(+K2/V2),
// flash2.

typedef __bf16 bf16;
typedef bf16 bf16x2 __attribute__((ext_vector_type(2)));
typedef bf16 bf16x4 __attribute__((ext_vector_type(4)));
typedef bf16 bf16x8 __attribute__((ext_vector_type(8)));
typedef float f32x4 __attribute__((ext_vector_type(4)));
typedef float f32x16 __attribute__((ext_vector_type(16)));
typedef unsigned int u32;
typedef u32 u32x4 __attribute__((ext_vector_type(4)));

#define MFMA32(a, b, c) __builtin_amdgcn_mfma_f32_32x32x16_bf16(a, b, c, 0, 0, 0)
#define ZERO16 {0,0,0,0,0,0,0,0,0,0,0,0,0,0,0,0}
#define LOG2E 1.44269504f

__device__ __forceinline__ float fast_exp2(float x) {
  return __builtin_amdgcn_exp2f(x);  // v_exp_f32: 2^x, single instruction
}
__device__ __forceinline__ float fast_sigmoid(float x) {
  return __builtin_amdgcn_rcpf(1.0f + fast_exp2(-LOG2E * x));
}
__device__ __forceinline__ u32 cvt_pk_bf16(float lo, float hi) {
  u32 r;
  asm("v_cvt_pk_bf16_f32 %0, %1, %2" : "=v"(r) : "v"(lo), "v"(hi));
  return r;
}
// v_permlane32_swap_b32: a[lanes 32:63] <-> b[lanes 0:31]
__device__ __forceinline__ void pl32_swap(u32& a, u32& b) {
  asm("v_permlane32_swap_b32 %0, %1" : "+v"(a), "+v"(b));
}
// Convert one 32x32 MFMA C-tile (col = lane&31, row = (j&3)+8*(j>>2)+4*hi)
// into two A/B-operand bf16x8 fragments: f0 covers rows 0..15, f1 rows 16..31,
// lane&31 keeps its column index, hi selects the 8-row half.
__device__ __forceinline__ void build_frags(const f32x16 v, bf16x8& f0, bf16x8& f1) {
  u32 t0 = cvt_pk_bf16(v[0], v[1]);
  u32 t1 = cvt_pk_bf16(v[2], v[3]);
  u32 t2 = cvt_pk_bf16(v[4], v[5]);
  u32 t3 = cvt_pk_bf16(v[6], v[7]);
  pl32_swap(t0, t2);
  pl32_swap(t1, t3);
  u32x4 a = {t0, t1, t2, t3};
  f0 = __builtin_bit_cast(bf16x8, a);
  u32 s0 = cvt_pk_bf16(v[8], v[9]);
  u32 s1 = cvt_pk_bf16(v[10], v[11]);
  u32 s2 = cvt_pk_bf16(v[12], v[13]);
  u32 s3 = cvt_pk_bf16(v[14], v[15]);
  pl32_swap(s0, s2);
  pl32_swap(s1, s3);
  u32x4 c = {s0, s1, s2, s3};
  f1 = __builtin_bit_cast(bf16x8, c);
}

// ---------------- prep: per-batch scale/bias + weight fp32->bf16 -----------
__global__ __launch_bounds__(256) void prep_kernel(
    const int* __restrict__ L,
    const float* __restrict__ wq0, const float* __restrict__ wqr,
    const float* __restrict__ wk0, const float* __restrict__ wkr,
    const float* __restrict__ wv0, const float* __restrict__ wvr,
    const float* __restrict__ wor, const float* __restrict__ wo_last,
    float* __restrict__ scale_inv, float* __restrict__ biasv,
    bf16* __restrict__ wbf) {
  __shared__ int red[256];
  const int blk = blockIdx.x;
  const int tid = threadIdx.x;
  if (blk < 64) {
    int cnt = 0;
    for (int n = tid; n < 1024; n += 256) cnt += (L[blk * 1024 + n] >= 1) ? 1 : 0;
    red[tid] = cnt;
    __syncthreads();
    for (int s = 128; s > 0; s >>= 1) {
      if (tid < s) red[tid] += red[tid + s];
      __syncthreads();
    }
    if (tid == 0) {
      float iv = rsqrtf((float)red[0] + 1.0f);
      scale_inv[blk] = iv;
      biasv[blk] = fmaxf(0.0f, 128.0f * iv * LOG2E - 80.0f);
    }
  } else {
    for (int i = (blk - 64) * 256 + tid; i < 163840; i += 64 * 256) {
      float v;
      if      (i <   8192) v = wq0[i];
      else if (i <  40960) v = wqr[i - 8192];
      else if (i <  49152) v = wk0[i - 40960];
      else if (i <  81920) v = wkr[i - 49152];
      else if (i <  90112) v = wv0[i - 81920];
      else if (i < 122880) v = wvr[i - 90112];
      else if (i < 155648) v = wor[i - 122880];
      else                 v = wo_last[i - 155648];
      wbf[i] = (bf16)v;
    }
  }
}

// ------------- xk0: transpose x tile + layer-0 K/V for same tokens ---------
__global__ __launch_bounds__(256) void xk0_kernel(
    const float* __restrict__ x, const bf16* __restrict__ Wk,
    const bf16* __restrict__ Wv, bf16* __restrict__ xT,
    bf16* __restrict__ Kt, bf16* __restrict__ Vn) {
  __shared__ float tile[64][65];
  __shared__ __attribute__((aligned(16))) bf16 inp_lds[64 * 72];
  const int tid = threadIdx.x;
  const int lane = tid & 63, wv = tid >> 6;
  const int la = lane & 31, hi = lane >> 5;
  const int b = blockIdx.x >> 4;
  const int t0 = (blockIdx.x & 15) * 64;

  {
    const int nl = tid & 63, dbase = (tid >> 6) * 16;
#pragma unroll
    for (int i = 0; i < 16; i++) {
      int d = dbase + i;
      tile[d][nl] = x[(size_t)(b * 64 + d) * 1024 + t0 + nl];
    }
  }
  __syncthreads();
  {
    const int dl = (tid & 31) * 2, nb = (tid >> 5) * 8;
#pragma unroll
    for (int i = 0; i < 8; i++) {
      int n = nb + i;
      bf16x2 pr = {(bf16)tile[dl][n], (bf16)tile[dl + 1][n]};
      *(bf16x2*)(xT + (size_t)(b * 1024 + t0 + n) * 64 + dl) = pr;
      *(bf16x2*)&inp_lds[n * 72 + dl] = pr;
    }
  }
  __syncthreads();

  const int sub = wv & 1;
  if (wv < 2) {
#pragma unroll
    for (int rt2 = 0; rt2 < 2; rt2++) {
      const int rt = 2 * sub + rt2;
      bf16x8 wf[4];
#pragma unroll
      for (int ks = 0; ks < 4; ks++)
        wf[ks] = *(const bf16x8*)(Wk + (size_t)(la + 32 * rt) * 64 + hi * 8 + ks * 16);
#pragma unroll
      for (int tt = 0; tt < 2; tt++) {
        f32x16 acc = ZERO16;
#pragma unroll
        for (int ks = 0; ks < 4; ks++) {
          bf16x8 bfr = *(const bf16x8*)&inp_lds[(la + 32 * tt) * 72 + hi * 8 + ks * 16];
          acc = MFMA32(wf[ks], bfr, acc);
        }
#pragma unroll
        for (int g = 0; g < 4; g++) {
          bf16x4 pk;
#pragma unroll
          for (int i = 0; i < 4; i++) pk[i] = (bf16)fast_sigmoid(acc[4 * g + i]);
          *(bf16x4*)(Kt + (size_t)(b * 1024 + t0 + 32 * tt + la) * 128 +
                     32 * rt + 8 * g + 4 * hi) = pk;
        }
      }
    }
  } else {
#pragma unroll
    for (int rc2 = 0; rc2 < 2; rc2++) {
      const int rc = 2 * sub + rc2;
      bf16x8 wf[4];
#pragma unroll
      for (int ks = 0; ks < 4; ks++)
        wf[ks] = *(const bf16x8*)(Wv + (size_t)(la + 32 * rc) * 64 + hi * 8 + ks * 16);
#pragma unroll
      for (int tt = 0; tt < 2; tt++) {
        f32x16 acc = ZERO16;
#pragma unroll
        for (int ks = 0; ks < 4; ks++) {
          bf16x8 afr = *(const bf16x8*)&inp_lds[(la + 32 * tt) * 72 + hi * 8 + ks * 16];
          acc = MFMA32(afr, wf[ks], acc);
        }
#pragma unroll
        for (int g = 0; g < 4; g++) {
          bf16x4 pk;
#pragma unroll
          for (int i = 0; i < 4; i++) pk[i] = (bf16)fast_sigmoid(acc[4 * g + i]);
          *(bf16x4*)(Vn + (size_t)(b * 128 + la + 32 * rc) * 1024 +
                     t0 + 32 * tt + 8 * g + 4 * hi) = pk;
        }
      }
    }
  }
}

// -------- standalone KV producer (fallback path only), 64 tokens/block -----
template <int DIN>
__global__ __launch_bounds__(256) void kv_kernel(
    const bf16* __restrict__ inpT, const bf16* __restrict__ Wk,
    const bf16* __restrict__ Wv, bf16* __restrict__ Kt,
    bf16* __restrict__ Vn) {
  constexpr int SIN = DIN + 8;
  constexpr int KS = DIN / 16;
  constexpr int CPR = DIN / 8;
  __shared__ __attribute__((aligned(16))) bf16 inp_lds[64 * SIN];
  const int tid = threadIdx.x;
  const int lane = tid & 63, wv = tid >> 6;
  const int la = lane & 31, hi = lane >> 5;
  const int b = blockIdx.x >> 4;
  const int t0 = (blockIdx.x & 15) * 64;

  for (int i = tid; i < 64 * CPR; i += 256) {
    int row = i / CPR, c = i % CPR;
    *(bf16x8*)&inp_lds[row * SIN + c * 8] =
        *(const bf16x8*)(inpT + (size_t)(b * 1024 + t0 + row) * DIN + c * 8);
  }
  __syncthreads();

  const int sub = wv & 1;
  if (wv < 2) {
#pragma unroll
    for (int rt2 = 0; rt2 < 2; rt2++) {
      const int rt = 2 * sub + rt2;
      bf16x8 wf[KS];
#pragma unroll
      for (int ks = 0; ks < KS; ks++)
        wf[ks] = *(const bf16x8*)(Wk + (size_t)(la + 32 * rt) * DIN + hi * 8 + ks * 16);
#pragma unroll
      for (int tt = 0; tt < 2; tt++) {
        f32x16 acc = ZERO16;
#pragma unroll
        for (int ks = 0; ks < KS; ks++) {
          bf16x8 bfr = *(const bf16x8*)&inp_lds[(la + 32 * tt) * SIN + hi * 8 + ks * 16];
          acc = MFMA32(wf[ks], bfr, acc);
        }
#pragma unroll
        for (int g = 0; g < 4; g++) {
          bf16x4 pk;
#pragma unroll
          for (int i = 0; i < 4; i++) pk[i] = (bf16)fast_sigmoid(acc[4 * g + i]);
          *(bf16x4*)(Kt + (size_t)(b * 1024 + t0 + 32 * tt + la) * 128 +
                     32 * rt + 8 * g + 4 * hi) = pk;
        }
      }
    }
  } else {
#pragma unroll
    for (int rc2 = 0; rc2 < 2; rc2++) {
      const int rc = 2 * sub + rc2;
      bf16x8 wf[KS];
#pragma unroll
      for (int ks = 0; ks < KS; ks++)
        wf[ks] = *(const bf16x8*)(Wv + (size_t)(la + 32 * rc) * DIN + hi * 8 + ks * 16);
#pragma unroll
      for (int tt = 0; tt < 2; tt++) {
        f32x16 acc = ZERO16;
#pragma unroll
        for (int ks = 0; ks < KS; ks++) {
          bf16x8 afr = *(const bf16x8*)&inp_lds[(la + 32 * tt) * SIN + hi * 8 + ks * 16];
          acc = MFMA32(afr, wf[ks], acc);
        }
#pragma unroll
        for (int g = 0; g < 4; g++) {
          bf16x4 pk;
#pragma unroll
          for (int i = 0; i < 4; i++) pk[i] = (bf16)fast_sigmoid(acc[4 * g + i]);
          *(bf16x4*)(Vn + (size_t)(b * 128 + 32 * rc + la) * 1024 +
                     t0 + 32 * tt + 8 * g + 4 * hi) = pk;
        }
      }
    }
  }
}

// ---------------- flash: Q-gen + attention + projection (+ next K/V) -------
// Block: 128 Q rows, 16 KV tiles of 64, 4 waves (wave wv owns q rows
// 32*wv..32*wv+31), 2 blocks/CU (grid 512). One __syncthreads per KV tile.
// LDS (71680 B): K0@0 (64x136) | K1@17408 | V0@34816 (128x72) | V1@53248
// prologue: inp_s 128x(DIN+8) @0 (dies before first K-tile write)
// epilogue: O_lds 128x136 @0 | rsp f32[128]@34816 | O2 128x136 @36864
// XCD swizzle: b = (blockIdx&7)*8 + ((blockIdx>>3)&7), q0 = (blockIdx>>6)*128.
template <int DIN>
__global__ __launch_bounds__(256, 2) void flash_kernel(
    const bf16* __restrict__ inpT, const bf16* __restrict__ Wq,
    const bf16* __restrict__ Kt, const bf16* __restrict__ Vn,
    const float* __restrict__ scale_inv, const float* __restrict__ biasv,
    const int* __restrict__ L, const bf16* __restrict__ Wo,
    void* __restrict__ outp, int last,
    const bf16* __restrict__ Wkn, const bf16* __restrict__ Wvn,
    bf16* __restrict__ Ktn, bf16* __restrict__ Vnn, int kvgen) {
  __shared__ __attribute__((aligned(16))) char smem[71680];

  const int tid = threadIdx.x;
  const int lane = tid & 63, wv = tid >> 6;
  const int la = lane & 31, hi = lane >> 5;
  const int xcd = blockIdx.x & 7;
  const int kk = blockIdx.x >> 3;
  const int b = xcd * 8 + (kk & 7);
  const int q0 = (kk >> 3) * 128;

  const float inv2 = scale_inv[b] * LOG2E;
  const float bb = biasv[b];

  const int krow = tid >> 4, kc = (tid & 15) * 8;
  const int vrow = tid >> 3, vc = (tid & 7) * 8;
  const bf16* kbase = Kt + (size_t)b * 1024 * 128;
  const bf16* vbase = Vn + (size_t)b * 128 * 1024;

  // tile-0 global loads issued first; latency hides under inp stage + Q-gen
  bf16x8 kr[4], vr[4];
#pragma unroll
  for (int p = 0; p < 4; p++) {
    kr[p] = *(const bf16x8*)(kbase + (size_t)(krow + 16 * p) * 128 + kc);
    vr[p] = *(const bf16x8*)(vbase + (size_t)(vrow + 32 * p) * 1024 + vc);
  }

  // ---- prologue: stage inp, Q' = sigmoid(Wq inp)*inv2 into register frags --
  bf16x8 qB[8];
  {
    constexpr int SIN = DIN + 8;
    constexpr int KSD = DIN / 16;
    constexpr int CPR = DIN / 8;
    bf16* inp_s = (bf16*)smem;
    for (int i = tid; i < 128 * CPR; i += 256) {
      int row = i / CPR, c = i % CPR;
      *(bf16x8*)&inp_s[row * SIN + c * 8] =
          *(const bf16x8*)(inpT + (size_t)(b * 1024 + q0 + row) * DIN + c * 8);
    }
    __syncthreads();
    bf16x8 bfr[KSD];
#pragma unroll
    for (int ks = 0; ks < KSD; ks++)
      bfr[ks] = *(const bf16x8*)&inp_s[(32 * wv + la) * SIN + hi * 8 + ks * 16];
#pragma unroll
    for (int rt = 0; rt < 4; rt++) {
      f32x16 acc = ZERO16;
#pragma unroll
      for (int ks = 0; ks < KSD; ks++) {
        bf16x8 wf = *(const bf16x8*)(Wq + (size_t)(32 * rt + la) * DIN +
                                     hi * 8 + ks * 16);
        acc = MFMA32(wf, bfr[ks], acc);
      }
      f32x16 qv;
#pragma unroll
      for (int j = 0; j < 16; j++) qv[j] = fast_sigmoid(acc[j]) * inv2;
      build_frags(qv, qB[2 * rt], qB[2 * rt + 1]);
    }
    __syncthreads();  // all waves done reading inp_s (K0 region reused below)
  }

  // stage tile 0 into buf0, prefetch tile 1
  {
    bf16* K0 = (bf16*)smem;
    bf16* V0 = (bf16*)(smem + 34816);
#pragma unroll
    for (int p = 0; p < 4; p++) *(bf16x8*)&K0[(krow + 16 * p) * 136 + kc] = kr[p];
#pragma unroll
    for (int p = 0; p < 4; p++) *(bf16x8*)&V0[(vrow + 32 * p) * 72 + vc] = vr[p];
#pragma unroll
    for (int p = 0; p < 4; p++) {
      kr[p] = *(const bf16x8*)(kbase + (size_t)(64 + krow + 16 * p) * 128 + kc);
      vr[p] = *(const bf16x8*)(vbase + (size_t)(vrow + 32 * p) * 1024 + 64 + vc);
    }
    __syncthreads();  // buf0 ready
  }

  f32x16 acc_o[4] = {ZERO16, ZERO16, ZERO16, ZERO16};
  float rs = 0.f;

  for (int it = 0; it < 16; it++) {
    const int cur = it & 1;
    const bf16* Kc = (const bf16*)(smem + cur * 17408);
    const bf16* Vc = (const bf16*)(smem + 34816 + cur * 18432);
    // write tile it+1 into the other buffer (read-protected by prev barrier)
    if (it < 15) {
      bf16* Kn = (bf16*)(smem + (1 - cur) * 17408);
      bf16* Vx = (bf16*)(smem + 34816 + (1 - cur) * 18432);
#pragma unroll
      for (int p = 0; p < 4; p++)
        *(bf16x8*)&Kn[(krow + 16 * p) * 136 + kc] = kr[p];
#pragma unroll
      for (int p = 0; p < 4; p++)
        *(bf16x8*)&Vx[(vrow + 32 * p) * 72 + vc] = vr[p];
    }
    if (it < 14) {
      const int m2 = (it + 2) * 64;
#pragma unroll
      for (int p = 0; p < 4; p++) {
        kr[p] = *(const bf16x8*)(kbase + (size_t)(m2 + krow + 16 * p) * 128 + kc);
        vr[p] = *(const bf16x8*)(vbase + (size_t)(vrow + 32 * p) * 1024 + m2 + vc);
      }
    }

    // QK^T (swapped: mfma(K,Q) -> col = own q token) + in-register softmax
    bf16x8 pa[4];
#pragma unroll
    for (int kt = 0; kt < 2; kt++) {
      f32x16 sa = ZERO16;
#pragma unroll
      for (int ks = 0; ks < 8; ks++) {
        bf16x8 kf = *(const bf16x8*)&Kc[(32 * kt + la) * 136 + hi * 8 + ks * 16];
        sa = MFMA32(kf, qB[ks], sa);
      }
      f32x16 pv;
#pragma unroll
      for (int j = 0; j < 16; j++) {
        float p = fast_exp2(sa[j] - bb);
        rs += p;
        pv[j] = p;
      }
      build_frags(pv, pa[2 * kt], pa[2 * kt + 1]);
    }

    // PV: out[q][r] += P[q][k] * V[r][k]
#pragma unroll
    for (int rt = 0; rt < 4; rt++) {
#pragma unroll
      for (int k2 = 0; k2 < 4; k2++) {
        bf16x8 vB = *(const bf16x8*)&Vc[(32 * rt + la) * 72 + hi * 8 + k2 * 16];
        acc_o[rt] = MFMA32(pa[k2], vB, acc_o[rt]);
      }
    }
    __syncthreads();  // tile it+1 writes visible; tile it reads done
  }

  // ---- epilogue: rowsums (wave-private), normalize, project ----
  rs += __shfl_xor(rs, 32, 64);
  float* rsp = (float*)(smem + 34816);
  if (lane < 32) rsp[32 * wv + la] = rs;
  bf16* O_lds = (bf16*)smem;
#pragma unroll
  for (int g = 0; g < 4; g++) {
    const int qb = 8 * g + 4 * hi;
    f32x4 r4 = *(f32x4*)&rsp[32 * wv + qb];
    f32x4 is;
#pragma unroll
    for (int i = 0; i < 4; i++) is[i] = 1.0f / r4[i];
#pragma unroll
    for (int rt = 0; rt < 4; rt++) {
#pragma unroll
      for (int i = 0; i < 4; i++) {
        O_lds[(size_t)(32 * wv + qb + i) * 136 + 32 * rt + la] =
            (bf16)(acc_o[rt][4 * g + i] * is[i]);
      }
    }
  }
  __syncthreads();  // (F) O_lds complete

  if (!last) {
    bf16* out_b = (bf16*)outp;
    bf16* O2 = (bf16*)(smem + 36864);  // post-silu tokens, token-major
    const int* Lg = L + b * 1024 + q0;
    bf16x8 wB[8];
#pragma unroll
    for (int ks = 0; ks < 8; ks++)
      wB[ks] = *(const bf16x8*)(Wo + (size_t)(la + 32 * wv) * 128 + hi * 8 + ks * 16);
#pragma unroll
    for (int nt = 0; nt < 4; nt++) {
      f32x16 acc = ZERO16;
#pragma unroll
      for (int ks = 0; ks < 8; ks++) {
        bf16x8 oA = *(const bf16x8*)&O_lds[(size_t)(la + 32 * nt) * 136 +
                                           hi * 8 + ks * 16];
        acc = MFMA32(oA, wB[ks], acc);
      }
#pragma unroll
      for (int g = 0; g < 4; g++) {
#pragma unroll
        for (int i = 0; i < 4; i++) {
          int n = 32 * nt + 8 * g + 4 * hi + i;
          float xv = acc[4 * g + i];
          float y = xv * fast_sigmoid(xv) * (float)Lg[n];
          out_b[(size_t)(b * 1024 + q0 + n) * 128 + 32 * wv + la] = (bf16)y;
          if (kvgen) O2[(size_t)n * 136 + 32 * wv + la] = (bf16)y;
        }
      }
    }
    if (kvgen) {
      __syncthreads();  // (G) O2 complete
      const bf16* O2c = (const bf16*)(smem + 36864);
      const int sub = wv & 1;
      const bf16* W2 = (wv < 2) ? Wkn : Wvn;
#pragma unroll
      for (int rt2 = 0; rt2 < 2; rt2++) {
        const int rt = 2 * sub + rt2;
        bf16x8 wf[8];
#pragma unroll
        for (int ks = 0; ks < 8; ks++)
          wf[ks] = *(const bf16x8*)(W2 + (size_t)(la + 32 * rt) * 128 +
                                    hi * 8 + ks * 16);
#pragma unroll
        for (int tt = 0; tt < 4; tt++) {
          f32x16 acc = ZERO16;
          if (wv < 2) {
#pragma unroll
            for (int ks = 0; ks < 8; ks++) {
              bf16x8 bB = *(const bf16x8*)&O2c[(size_t)(32 * tt + la) * 136 +
                                               hi * 8 + ks * 16];
              acc = MFMA32(wf[ks], bB, acc);
            }
#pragma unroll
            for (int g = 0; g < 4; g++) {
              bf16x4 pk;
#pragma unroll
              for (int i = 0; i < 4; i++) pk[i] = (bf16)fast_sigmoid(acc[4 * g + i]);
              *(bf16x4*)(Ktn + (size_t)(b * 1024 + q0 + 32 * tt + la) * 128 +
                         32 * rt + 8 * g + 4 * hi) = pk;
            }
          } else {
#pragma unroll
            for (int ks = 0; ks < 8; ks++) {
              bf16x8 aA = *(const bf16x8*)&O2c[(size_t)(32 * tt + la) * 136 +
                                               hi * 8 + ks * 16];
              acc = MFMA32(aA, wf[ks], acc);
            }
#pragma unroll
            for (int g = 0; g < 4; g++) {
              bf16x4 pk;
#pragma unroll
              for (int i = 0; i < 4; i++) pk[i] = (bf16)fast_sigmoid(acc[4 * g + i]);
              *(bf16x4*)(Vnn + (size_t)(b * 128 + 32 * rt + la) * 1024 +
                         q0 + 32 * tt + 8 * g + 4 * hi) = pk;
            }
          }
        }
      }
    }
  } else {
    const int hs = wv & 1, nq = wv >> 1;
    float* outf = (float*)outp;
    bf16x8 wA[8];
#pragma unroll
    for (int ks = 0; ks < 8; ks++)
      wA[ks] = *(const bf16x8*)(Wo + (size_t)(la + 32 * hs) * 128 + hi * 8 + ks * 16);
#pragma unroll
    for (int t = 0; t < 2; t++) {
      const int ns4 = nq + 2 * t;
      f32x16 acc = ZERO16;
#pragma unroll
      for (int ks = 0; ks < 8; ks++) {
        bf16x8 oB = *(const bf16x8*)&O_lds[(size_t)(32 * ns4 + la) * 136 +
                                           hi * 8 + ks * 16];
        acc = MFMA32(wA[ks], oB, acc);
      }
#pragma unroll
      for (int g = 0; g < 4; g++) {
#pragma unroll
        for (int i = 0; i < 4; i++) {
          int h = 32 * hs + 8 * g + 4 * hi + i;
          float xv = acc[4 * g + i];
          outf[(size_t)(b * 64 + h) * 1024 + q0 + 32 * ns4 + la] =
              xv * fast_sigmoid(xv);
        }
      }
    }
  }
}

// ---------------- transpose x (fallback path) ------------------------------
__global__ __launch_bounds__(256) void xpose_kernel(const float* __restrict__ x,
                                                    bf16* __restrict__ xT) {
  __shared__ float tile[64][65];
  const int blk = blockIdx.x;
  const int b = blk >> 4;
  const int n0 = (blk & 15) * 64;
  const int tid = threadIdx.x;
  {
    const int nl = tid & 63, dbase = (tid >> 6) * 16;
#pragma unroll
    for (int i = 0; i < 16; i++) {
      int d = dbase + i;
      tile[d][nl] = x[(size_t)(b * 64 + d) * 1024 + n0 + nl];
    }
  }
  __syncthreads();
  {
    const int dl = (tid & 31) * 2, nb = (tid >> 5) * 8;
#pragma unroll
    for (int i = 0; i < 8; i++) {
      int n = nb + i;
      bf16x2 pr = {(bf16)tile[dl][n], (bf16)tile[dl + 1][n]};
      *(bf16x2*)(xT + (size_t)(b * 1024 + n0 + n) * 64 + dl) = pr;
    }
  }
}

// ---------------- host launch ----------------
extern "C" void kernel_launch(void* const* d_in, const int* in_sizes, int n_in,
                              void* d_out, int out_size, void* d_ws, size_t ws_size,
                              hipStream_t stream) {
  const float* x = (const float*)d_in[0];
  const int* L = (const int*)d_in[1];
  const float* wq0 = (const float*)d_in[2];
  const float* wqr = (const float*)d_in[3];
  const float* wk0 = (const float*)d_in[4];
  const float* wkr = (const float*)d_in[5];
  const float* wv0 = (const float*)d_in[6];
  const float* wvr = (const float*)d_in[7];
  const float* wor = (const float*)d_in[8];
  const float* wo_last = (const float*)d_in[9];

  char* ws = (char*)d_ws;
  float* scale_inv = (float*)(ws + 0);
  float* biasv = (float*)(ws + 1024);
  bf16* wbf = (bf16*)(ws + 4096);
  bf16* xT = (bf16*)(ws + 335872);
  bf16* inpT = (bf16*)(ws + 8724480);
  bf16* KtA = (bf16*)(ws + 25501696);
  bf16* VnA = (bf16*)(ws + 42278912);
  bf16* KtB = (bf16*)(ws + 59056128);
  bf16* VnB = (bf16*)(ws + 75833344);
  // bf16 weight offsets: wq0@0 wqr@8192 wk0@40960 wkr@49152 wv0@81920
  //                      wvr@90112 wor@122880 wo_last@155648

  prep_kernel<<<128, 256, 0, stream>>>(L, wq0, wqr, wk0, wkr, wv0, wvr, wor,
                                       wo_last, scale_inv, biasv, wbf);

  if (ws_size >= 92610560) {
    xk0_kernel<<<1024, 256, 0, stream>>>(x, wbf + 40960, wbf + 81920, xT, KtA, VnA);
    flash_kernel<64><<<512, 256, 0, stream>>>(
        xT, wbf + 0, KtA, VnA, scale_inv, biasv, L, wbf + 122880, (void*)inpT, 0,
        wbf + 49152, wbf + 90112, KtB, VnB, 1);
    flash_kernel<128><<<512, 256, 0, stream>>>(
        inpT, wbf + 8192, KtB, VnB, scale_inv, biasv, L, wbf + 139264,
        (void*)inpT, 0, wbf + 65536, wbf + 106496, KtA, VnA, 1);
    flash_kernel<128><<<512, 256, 0, stream>>>(
        inpT, wbf + 24576, KtA, VnA, scale_inv, biasv, L, wbf + 155648, d_out, 1,
        nullptr, nullptr, nullptr, nullptr, 0);
  } else if (ws_size >= 59056128) {
    xpose_kernel<<<1024, 256, 0, stream>>>(x, xT);
    for (int l = 0; l < 3; l++) {
      const bf16* Wq = (l == 0) ? wbf + 0 : wbf + 8192 + (size_t)(l - 1) * 16384;
      const bf16* Wk = (l == 0) ? wbf + 40960 : wbf + 49152 + (size_t)(l - 1) * 16384;
      const bf16* Wv = (l == 0) ? wbf + 81920 : wbf + 90112 + (size_t)(l - 1) * 16384;
      const bf16* Wo = (l < 2) ? wbf + 122880 + (size_t)l * 16384 : wbf + 155648;
      void* outp = (l < 2) ? (void*)inpT : (void*)d_out;
      if (l == 0) {
        kv_kernel<64><<<1024, 256, 0, stream>>>(xT, Wk, Wv, KtA, VnA);
        flash_kernel<64><<<512, 256, 0, stream>>>(xT, Wq, KtA, VnA, scale_inv,
                                                  biasv, L, Wo, outp, 0,
                                                  nullptr, nullptr, nullptr,
                                                  nullptr, 0);
      } else {
        kv_kernel<128><<<1024, 256, 0, stream>>>(inpT, Wk, Wv, KtA, VnA);
        flash_kernel<128><<<512, 256, 0, stream>>>(inpT, Wq, KtA, VnA, scale_inv,
                                                   biasv, L, Wo, outp,
                                                   (l == 2) ? 1 : 0, nullptr,
                                                   nullptr, nullptr, nullptr, 0);
      }
    }
  }
}

// Round 5
// 272.469 us; speedup vs baseline: 1.0042x; 1.0042x over previous
//
#include <hip/hip_runtime.h>

// AttentionModule: 3-layer sigmoid-QKV attention, B=64 N=1024 R=128 D=64 H=64.
// R16 = R12 base (validated 273.6us; 256-thread, 4-wave, single-barrier loop,
// in-register softmax) + ILP attack on dependent-latency:
//  - QK: 2x8-dep MFMA chains -> 4 independent chains of 4 (kt-interleaved),
//    summed before exp (s00+s01, s10+s11)
//  - rowsum: serial 32-add chain -> tree (depth ~5)
//  - T5 s_setprio(1) around QK and PV MFMA clusters
// 512-thread occupancy push (R13-R15) aborted 2x on-device with no counters;
// abandoned pending infra diagnosis. R12 evidence: NOT barrier/LDS-conflict/
// HBM-bound; pipes ~25% each at 2 waves/SIMD. This tests the latency theory
// at fixed occupancy. If flat -> limiter is LDS pipe / issue rate.

typedef __bf16 bf16;
typedef bf16 bf16x2 __attribute__((ext_vector_type(2)));
typedef bf16 bf16x4 __attribute__((ext_vector_type(4)));
typedef bf16 bf16x8 __attribute__((ext_vector_type(8)));
typedef float f32x4 __attribute__((ext_vector_type(4)));
typedef float f32x16 __attribute__((ext_vector_type(16)));
typedef unsigned int u32;
typedef u32 u32x4 __attribute__((ext_vector_type(4)));

#define MFMA32(a, b, c) __builtin_amdgcn_mfma_f32_32x32x16_bf16(a, b, c, 0, 0, 0)
#define ZERO16 {0,0,0,0,0,0,0,0,0,0,0,0,0,0,0,0}
#define LOG2E 1.44269504f

__device__ __forceinline__ float fast_exp2(float x) {
  return __builtin_amdgcn_exp2f(x);
}
__device__ __forceinline__ float fast_sigmoid(float x) {
  return __builtin_amdgcn_rcpf(1.0f + fast_exp2(-LOG2E * x));
}
__device__ __forceinline__ u32 cvt_pk_bf16(float lo, float hi) {
  u32 r;
  asm("v_cvt_pk_bf16_f32 %0, %1, %2" : "=v"(r) : "v"(lo), "v"(hi));
  return r;
}
__device__ __forceinline__ void pl32_swap(u32& a, u32& b) {
  asm("v_permlane32_swap_b32 %0, %1" : "+v"(a), "+v"(b));
}
// C-tile (col=lane&31, row=(j&3)+8*(j>>2)+4*hi) -> two operand fragments:
// f0 rows 0..15, f1 rows 16..31; lane keeps its column index (validated R12).
__device__ __forceinline__ void build_frags(const f32x16 v, bf16x8& f0, bf16x8& f1) {
  u32 t0 = cvt_pk_bf16(v[0], v[1]);
  u32 t1 = cvt_pk_bf16(v[2], v[3]);
  u32 t2 = cvt_pk_bf16(v[4], v[5]);
  u32 t3 = cvt_pk_bf16(v[6], v[7]);
  pl32_swap(t0, t2);
  pl32_swap(t1, t3);
  u32x4 a = {t0, t1, t2, t3};
  f0 = __builtin_bit_cast(bf16x8, a);
  u32 s0 = cvt_pk_bf16(v[8], v[9]);
  u32 s1 = cvt_pk_bf16(v[10], v[11]);
  u32 s2 = cvt_pk_bf16(v[12], v[13]);
  u32 s3 = cvt_pk_bf16(v[14], v[15]);
  pl32_swap(s0, s2);
  pl32_swap(s1, s3);
  u32x4 c = {s0, s1, s2, s3};
  f1 = __builtin_bit_cast(bf16x8, c);
}
__device__ __forceinline__ float treesum16(const f32x16 v) {
  float a0 = v[0] + v[1], a1 = v[2] + v[3], a2 = v[4] + v[5], a3 = v[6] + v[7];
  float a4 = v[8] + v[9], a5 = v[10] + v[11], a6 = v[12] + v[13], a7 = v[14] + v[15];
  float b0 = a0 + a1, b1 = a2 + a3, b2 = a4 + a5, b3 = a6 + a7;
  return (b0 + b1) + (b2 + b3);
}

// ---------------- prep: per-batch scale/bias + weight fp32->bf16 -----------
__global__ __launch_bounds__(256) void prep_kernel(
    const int* __restrict__ L,
    const float* __restrict__ wq0, const float* __restrict__ wqr,
    const float* __restrict__ wk0, const float* __restrict__ wkr,
    const float* __restrict__ wv0, const float* __restrict__ wvr,
    const float* __restrict__ wor, const float* __restrict__ wo_last,
    float* __restrict__ scale_inv, float* __restrict__ biasv,
    bf16* __restrict__ wbf) {
  __shared__ int red[256];
  const int blk = blockIdx.x;
  const int tid = threadIdx.x;
  if (blk < 64) {
    int cnt = 0;
    for (int n = tid; n < 1024; n += 256) cnt += (L[blk * 1024 + n] >= 1) ? 1 : 0;
    red[tid] = cnt;
    __syncthreads();
    for (int s = 128; s > 0; s >>= 1) {
      if (tid < s) red[tid] += red[tid + s];
      __syncthreads();
    }
    if (tid == 0) {
      float iv = rsqrtf((float)red[0] + 1.0f);
      scale_inv[blk] = iv;
      biasv[blk] = fmaxf(0.0f, 128.0f * iv * LOG2E - 80.0f);
    }
  } else {
    for (int i = (blk - 64) * 256 + tid; i < 163840; i += 64 * 256) {
      float v;
      if      (i <   8192) v = wq0[i];
      else if (i <  40960) v = wqr[i - 8192];
      else if (i <  49152) v = wk0[i - 40960];
      else if (i <  81920) v = wkr[i - 49152];
      else if (i <  90112) v = wv0[i - 81920];
      else if (i < 122880) v = wvr[i - 90112];
      else if (i < 155648) v = wor[i - 122880];
      else                 v = wo_last[i - 155648];
      wbf[i] = (bf16)v;
    }
  }
}

// ------------- xk0: transpose x tile + layer-0 K/V for same tokens ---------
__global__ __launch_bounds__(256) void xk0_kernel(
    const float* __restrict__ x, const bf16* __restrict__ Wk,
    const bf16* __restrict__ Wv, bf16* __restrict__ xT,
    bf16* __restrict__ Kt, bf16* __restrict__ Vn) {
  __shared__ float tile[64][65];
  __shared__ __attribute__((aligned(16))) bf16 inp_lds[64 * 72];
  const int tid = threadIdx.x;
  const int lane = tid & 63, wv = tid >> 6;
  const int la = lane & 31, hi = lane >> 5;
  const int b = blockIdx.x >> 4;
  const int t0 = (blockIdx.x & 15) * 64;

  {
    const int nl = tid & 63, dbase = (tid >> 6) * 16;
#pragma unroll
    for (int i = 0; i < 16; i++) {
      int d = dbase + i;
      tile[d][nl] = x[(size_t)(b * 64 + d) * 1024 + t0 + nl];
    }
  }
  __syncthreads();
  {
    const int dl = (tid & 31) * 2, nb = (tid >> 5) * 8;
#pragma unroll
    for (int i = 0; i < 8; i++) {
      int n = nb + i;
      bf16x2 pr = {(bf16)tile[dl][n], (bf16)tile[dl + 1][n]};
      *(bf16x2*)(xT + (size_t)(b * 1024 + t0 + n) * 64 + dl) = pr;
      *(bf16x2*)&inp_lds[n * 72 + dl] = pr;
    }
  }
  __syncthreads();

  const int sub = wv & 1;
  if (wv < 2) {
#pragma unroll
    for (int rt2 = 0; rt2 < 2; rt2++) {
      const int rt = 2 * sub + rt2;
      bf16x8 wf[4];
#pragma unroll
      for (int ks = 0; ks < 4; ks++)
        wf[ks] = *(const bf16x8*)(Wk + (size_t)(la + 32 * rt) * 64 + hi * 8 + ks * 16);
#pragma unroll
      for (int tt = 0; tt < 2; tt++) {
        f32x16 acc = ZERO16;
#pragma unroll
        for (int ks = 0; ks < 4; ks++) {
          bf16x8 bfr = *(const bf16x8*)&inp_lds[(la + 32 * tt) * 72 + hi * 8 + ks * 16];
          acc = MFMA32(wf[ks], bfr, acc);
        }
#pragma unroll
        for (int g = 0; g < 4; g++) {
          bf16x4 pk;
#pragma unroll
          for (int i = 0; i < 4; i++) pk[i] = (bf16)fast_sigmoid(acc[4 * g + i]);
          *(bf16x4*)(Kt + (size_t)(b * 1024 + t0 + 32 * tt + la) * 128 +
                     32 * rt + 8 * g + 4 * hi) = pk;
        }
      }
    }
  } else {
#pragma unroll
    for (int rc2 = 0; rc2 < 2; rc2++) {
      const int rc = 2 * sub + rc2;
      bf16x8 wf[4];
#pragma unroll
      for (int ks = 0; ks < 4; ks++)
        wf[ks] = *(const bf16x8*)(Wv + (size_t)(la + 32 * rc) * 64 + hi * 8 + ks * 16);
#pragma unroll
      for (int tt = 0; tt < 2; tt++) {
        f32x16 acc = ZERO16;
#pragma unroll
        for (int ks = 0; ks < 4; ks++) {
          bf16x8 afr = *(const bf16x8*)&inp_lds[(la + 32 * tt) * 72 + hi * 8 + ks * 16];
          acc = MFMA32(afr, wf[ks], acc);
        }
#pragma unroll
        for (int g = 0; g < 4; g++) {
          bf16x4 pk;
#pragma unroll
          for (int i = 0; i < 4; i++) pk[i] = (bf16)fast_sigmoid(acc[4 * g + i]);
          *(bf16x4*)(Vn + (size_t)(b * 128 + la + 32 * rc) * 1024 +
                     t0 + 32 * tt + 8 * g + 4 * hi) = pk;
        }
      }
    }
  }
}

// -------- standalone KV producer (fallback path only), 64 tokens/block -----
template <int DIN>
__global__ __launch_bounds__(256) void kv_kernel(
    const bf16* __restrict__ inpT, const bf16* __restrict__ Wk,
    const bf16* __restrict__ Wv, bf16* __restrict__ Kt,
    bf16* __restrict__ Vn) {
  constexpr int SIN = DIN + 8;
  constexpr int KS = DIN / 16;
  constexpr int CPR = DIN / 8;
  __shared__ __attribute__((aligned(16))) bf16 inp_lds[64 * SIN];
  const int tid = threadIdx.x;
  const int lane = tid & 63, wv = tid >> 6;
  const int la = lane & 31, hi = lane >> 5;
  const int b = blockIdx.x >> 4;
  const int t0 = (blockIdx.x & 15) * 64;

  for (int i = tid; i < 64 * CPR; i += 256) {
    int row = i / CPR, c = i % CPR;
    *(bf16x8*)&inp_lds[row * SIN + c * 8] =
        *(const bf16x8*)(inpT + (size_t)(b * 1024 + t0 + row) * DIN + c * 8);
  }
  __syncthreads();

  const int sub = wv & 1;
  if (wv < 2) {
#pragma unroll
    for (int rt2 = 0; rt2 < 2; rt2++) {
      const int rt = 2 * sub + rt2;
      bf16x8 wf[KS];
#pragma unroll
      for (int ks = 0; ks < KS; ks++)
        wf[ks] = *(const bf16x8*)(Wk + (size_t)(la + 32 * rt) * DIN + hi * 8 + ks * 16);
#pragma unroll
      for (int tt = 0; tt < 2; tt++) {
        f32x16 acc = ZERO16;
#pragma unroll
        for (int ks = 0; ks < KS; ks++) {
          bf16x8 bfr = *(const bf16x8*)&inp_lds[(la + 32 * tt) * SIN + hi * 8 + ks * 16];
          acc = MFMA32(wf[ks], bfr, acc);
        }
#pragma unroll
        for (int g = 0; g < 4; g++) {
          bf16x4 pk;
#pragma unroll
          for (int i = 0; i < 4; i++) pk[i] = (bf16)fast_sigmoid(acc[4 * g + i]);
          *(bf16x4*)(Kt + (size_t)(b * 1024 + t0 + 32 * tt + la) * 128 +
                     32 * rt + 8 * g + 4 * hi) = pk;
        }
      }
    }
  } else {
#pragma unroll
    for (int rc2 = 0; rc2 < 2; rc2++) {
      const int rc = 2 * sub + rc2;
      bf16x8 wf[KS];
#pragma unroll
      for (int ks = 0; ks < KS; ks++)
        wf[ks] = *(const bf16x8*)(Wv + (size_t)(la + 32 * rc) * DIN + hi * 8 + ks * 16);
#pragma unroll
      for (int tt = 0; tt < 2; tt++) {
        f32x16 acc = ZERO16;
#pragma unroll
        for (int ks = 0; ks < KS; ks++) {
          bf16x8 afr = *(const bf16x8*)&inp_lds[(la + 32 * tt) * SIN + hi * 8 + ks * 16];
          acc = MFMA32(afr, wf[ks], acc);
        }
#pragma unroll
        for (int g = 0; g < 4; g++) {
          bf16x4 pk;
#pragma unroll
          for (int i = 0; i < 4; i++) pk[i] = (bf16)fast_sigmoid(acc[4 * g + i]);
          *(bf16x4*)(Vn + (size_t)(b * 128 + 32 * rc + la) * 1024 +
                     t0 + 32 * tt + 8 * g + 4 * hi) = pk;
        }
      }
    }
  }
}

// ---------------- flash: Q-gen + attention + projection (+ next K/V) -------
// R12 structure: 256 threads, 4 waves, wave wv owns q rows 32wv..+31, full
// 64-token KV tile per wave, one barrier per tile (double-buffered K/V).
// LDS 71680: K0@0 [64][136] | K1@17408 | V0@34816 [128][72] | V1@53248.
// R16 delta: QK as 4 independent MFMA chains (kt-interleaved, chain-split),
// tree rowsum, setprio around MFMA clusters.
template <int DIN>
__global__ __launch_bounds__(256, 2) void flash_kernel(
    const bf16* __restrict__ inpT, const bf16* __restrict__ Wq,
    const bf16* __restrict__ Kt, const bf16* __restrict__ Vn,
    const float* __restrict__ scale_inv, const float* __restrict__ biasv,
    const int* __restrict__ L, const bf16* __restrict__ Wo,
    void* __restrict__ outp, int last,
    const bf16* __restrict__ Wkn, const bf16* __restrict__ Wvn,
    bf16* __restrict__ Ktn, bf16* __restrict__ Vnn, int kvgen) {
  __shared__ __attribute__((aligned(16))) char smem[71680];

  const int tid = threadIdx.x;
  const int lane = tid & 63, wv = tid >> 6;
  const int la = lane & 31, hi = lane >> 5;
  const int xcd = blockIdx.x & 7;
  const int kk = blockIdx.x >> 3;
  const int b = xcd * 8 + (kk & 7);
  const int q0 = (kk >> 3) * 128;

  const float inv2 = scale_inv[b] * LOG2E;
  const float bb = biasv[b];

  // staging: K tile 64x128 (pad 136), V tile 128x64 (pad 72)
  const int krow = tid >> 4, kc = (tid & 15) * 8;
  const int vrow = tid >> 3, vc = (tid & 7) * 8;
  const bf16* kbase = Kt + (size_t)b * 1024 * 128;
  const bf16* vbase = Vn + (size_t)b * 128 * 1024;

  bf16x8 kr[4], vr[4];
#pragma unroll
  for (int p = 0; p < 4; p++) {  // tile 0, issued before prologue to hide lat
    kr[p] = *(const bf16x8*)(kbase + (size_t)(krow + 16 * p) * 128 + kc);
    vr[p] = *(const bf16x8*)(vbase + (size_t)(vrow + 32 * p) * 1024 + vc);
  }

  // ---- prologue: stage inp, Q' = sigmoid(Wq inp)*inv2 into register frags --
  bf16x8 qB[8];
  {
    constexpr int SIN = DIN + 8;
    constexpr int KSD = DIN / 16;
    constexpr int CPR = DIN / 8;
    bf16* inp_s = (bf16*)smem;
    for (int i = tid; i < 128 * CPR; i += 256) {
      int row = i / CPR, c = i % CPR;
      *(bf16x8*)&inp_s[row * SIN + c * 8] =
          *(const bf16x8*)(inpT + (size_t)(b * 1024 + q0 + row) * DIN + c * 8);
    }
    __syncthreads();
    bf16x8 bfr[KSD];
#pragma unroll
    for (int ks = 0; ks < KSD; ks++)
      bfr[ks] = *(const bf16x8*)&inp_s[(32 * wv + la) * SIN + hi * 8 + ks * 16];
#pragma unroll
    for (int rt = 0; rt < 4; rt++) {
      f32x16 acc = ZERO16;
#pragma unroll
      for (int ks = 0; ks < KSD; ks++) {
        bf16x8 wf = *(const bf16x8*)(Wq + (size_t)(32 * rt + la) * DIN +
                                     hi * 8 + ks * 16);
        acc = MFMA32(wf, bfr[ks], acc);
      }
      f32x16 qv;
#pragma unroll
      for (int j = 0; j < 16; j++) qv[j] = fast_sigmoid(acc[j]) * inv2;
      build_frags(qv, qB[2 * rt], qB[2 * rt + 1]);
    }
    __syncthreads();  // inp_s dead (overlaps K buffers)
  }

  // stage tile 0 into buf0, load tile 1
  {
    bf16* K0 = (bf16*)smem;
    bf16* V0 = (bf16*)(smem + 34816);
#pragma unroll
    for (int p = 0; p < 4; p++) *(bf16x8*)&K0[(krow + 16 * p) * 136 + kc] = kr[p];
#pragma unroll
    for (int p = 0; p < 4; p++) *(bf16x8*)&V0[(vrow + 32 * p) * 72 + vc] = vr[p];
#pragma unroll
    for (int p = 0; p < 4; p++) {
      kr[p] = *(const bf16x8*)(kbase + (size_t)(64 + krow + 16 * p) * 128 + kc);
      vr[p] = *(const bf16x8*)(vbase + (size_t)(vrow + 32 * p) * 1024 + 64 + vc);
    }
    __syncthreads();  // buf0 ready
  }

  f32x16 acc_o[4] = {ZERO16, ZERO16, ZERO16, ZERO16};
  float rs = 0.f;

  for (int it = 0; it < 16; it++) {
    const int cur = it & 1;
    const bf16* Kc = (const bf16*)(smem + cur * 17408);
    const bf16* Vc = (const bf16*)(smem + 34816 + cur * 18432);
    if (it < 15) {  // write tile it+1 into other buffer
      bf16* Kn = (bf16*)(smem + (1 - cur) * 17408);
      bf16* Vx = (bf16*)(smem + 34816 + (1 - cur) * 18432);
#pragma unroll
      for (int p = 0; p < 4; p++)
        *(bf16x8*)&Kn[(krow + 16 * p) * 136 + kc] = kr[p];
#pragma unroll
      for (int p = 0; p < 4; p++)
        *(bf16x8*)&Vx[(vrow + 32 * p) * 72 + vc] = vr[p];
    }
    if (it < 14) {  // prefetch tile it+2
      const int m2 = (it + 2) * 64;
#pragma unroll
      for (int p = 0; p < 4; p++) {
        kr[p] = *(const bf16x8*)(kbase + (size_t)(m2 + krow + 16 * p) * 128 + kc);
        vr[p] = *(const bf16x8*)(vbase + (size_t)(vrow + 32 * p) * 1024 + m2 + vc);
      }
    }

    // QK^T (swapped: col = own q token), 4 independent MFMA chains of 4
    f32x16 s00 = ZERO16, s01 = ZERO16, s10 = ZERO16, s11 = ZERO16;
    __builtin_amdgcn_s_setprio(1);
#pragma unroll
    for (int ks = 0; ks < 4; ks++) {
      bf16x8 k0a = *(const bf16x8*)&Kc[la * 136 + hi * 8 + ks * 16];
      s00 = MFMA32(k0a, qB[ks], s00);
      bf16x8 k0b = *(const bf16x8*)&Kc[la * 136 + hi * 8 + (ks + 4) * 16];
      s01 = MFMA32(k0b, qB[ks + 4], s01);
      bf16x8 k1a = *(const bf16x8*)&Kc[(32 + la) * 136 + hi * 8 + ks * 16];
      s10 = MFMA32(k1a, qB[ks], s10);
      bf16x8 k1b = *(const bf16x8*)&Kc[(32 + la) * 136 + hi * 8 + (ks + 4) * 16];
      s11 = MFMA32(k1b, qB[ks + 4], s11);
    }
    __builtin_amdgcn_s_setprio(0);

    // in-register softmax (fixed bias), tree rowsum, P -> operand frags
    bf16x8 pa[4];
    {
      f32x16 pv;
#pragma unroll
      for (int j = 0; j < 16; j++) pv[j] = fast_exp2(s00[j] + s01[j] - bb);
      rs += treesum16(pv);
      build_frags(pv, pa[0], pa[1]);
    }
    {
      f32x16 pv;
#pragma unroll
      for (int j = 0; j < 16; j++) pv[j] = fast_exp2(s10[j] + s11[j] - bb);
      rs += treesum16(pv);
      build_frags(pv, pa[2], pa[3]);
    }

    // PV: out[q][r] += P[q][k] * V[r][k]; 4 independent acc chains
    __builtin_amdgcn_s_setprio(1);
#pragma unroll
    for (int rt = 0; rt < 4; rt++) {
#pragma unroll
      for (int k2 = 0; k2 < 4; k2++) {
        bf16x8 vB = *(const bf16x8*)&Vc[(32 * rt + la) * 72 + hi * 8 + k2 * 16];
        acc_o[rt] = MFMA32(pa[k2], vB, acc_o[rt]);
      }
    }
    __builtin_amdgcn_s_setprio(0);
    __syncthreads();
  }

  // ---- epilogue: rowsums (wave-private), normalize, project (R12) ----
  rs += __shfl_xor(rs, 32, 64);
  float* rsp = (float*)(smem + 34816);
  if (lane < 32) rsp[32 * wv + la] = rs;
  bf16* O_lds = (bf16*)smem;
#pragma unroll
  for (int g = 0; g < 4; g++) {
    const int qb = 8 * g + 4 * hi;
    f32x4 r4 = *(f32x4*)&rsp[32 * wv + qb];
    f32x4 is;
#pragma unroll
    for (int i = 0; i < 4; i++) is[i] = 1.0f / r4[i];
#pragma unroll
    for (int rt = 0; rt < 4; rt++) {
#pragma unroll
      for (int i = 0; i < 4; i++) {
        O_lds[(size_t)(32 * wv + qb + i) * 136 + 32 * rt + la] =
            (bf16)(acc_o[rt][4 * g + i] * is[i]);
      }
    }
  }
  __syncthreads();  // (F) O_lds complete

  if (!last) {
    bf16* out_b = (bf16*)outp;
    bf16* O2 = (bf16*)(smem + 36864);  // post-silu tokens, token-major
    const int* Lg = L + b * 1024 + q0;
    bf16x8 wB[8];
#pragma unroll
    for (int ks = 0; ks < 8; ks++)
      wB[ks] = *(const bf16x8*)(Wo + (size_t)(la + 32 * wv) * 128 + hi * 8 + ks * 16);
#pragma unroll
    for (int nt = 0; nt < 4; nt++) {
      f32x16 acc = ZERO16;
#pragma unroll
      for (int ks = 0; ks < 8; ks++) {
        bf16x8 oA = *(const bf16x8*)&O_lds[(size_t)(la + 32 * nt) * 136 +
                                           hi * 8 + ks * 16];
        acc = MFMA32(oA, wB[ks], acc);
      }
#pragma unroll
      for (int g = 0; g < 4; g++) {
#pragma unroll
        for (int i = 0; i < 4; i++) {
          int n = 32 * nt + 8 * g + 4 * hi + i;
          float xv = acc[4 * g + i];
          float y = xv * fast_sigmoid(xv) * (float)Lg[n];
          out_b[(size_t)(b * 1024 + q0 + n) * 128 + 32 * wv + la] = (bf16)y;
          if (kvgen) O2[(size_t)n * 136 + 32 * wv + la] = (bf16)y;
        }
      }
    }
    if (kvgen) {
      __syncthreads();  // (G) O2 complete
      const bf16* O2c = (const bf16*)(smem + 36864);
      const int sub = wv & 1;
      const bf16* W2 = (wv < 2) ? Wkn : Wvn;
#pragma unroll
      for (int rt2 = 0; rt2 < 2; rt2++) {
        const int rt = 2 * sub + rt2;
        bf16x8 wf[8];
#pragma unroll
        for (int ks = 0; ks < 8; ks++)
          wf[ks] = *(const bf16x8*)(W2 + (size_t)(la + 32 * rt) * 128 +
                                    hi * 8 + ks * 16);
#pragma unroll
        for (int tt = 0; tt < 4; tt++) {
          f32x16 acc = ZERO16;
          if (wv < 2) {
#pragma unroll
            for (int ks = 0; ks < 8; ks++) {
              bf16x8 bB = *(const bf16x8*)&O2c[(size_t)(32 * tt + la) * 136 +
                                               hi * 8 + ks * 16];
              acc = MFMA32(wf[ks], bB, acc);
            }
#pragma unroll
            for (int g = 0; g < 4; g++) {
              bf16x4 pk;
#pragma unroll
              for (int i = 0; i < 4; i++) pk[i] = (bf16)fast_sigmoid(acc[4 * g + i]);
              *(bf16x4*)(Ktn + (size_t)(b * 1024 + q0 + 32 * tt + la) * 128 +
                         32 * rt + 8 * g + 4 * hi) = pk;
            }
          } else {
#pragma unroll
            for (int ks = 0; ks < 8; ks++) {
              bf16x8 aA = *(const bf16x8*)&O2c[(size_t)(32 * tt + la) * 136 +
                                               hi * 8 + ks * 16];
              acc = MFMA32(aA, wf[ks], acc);
            }
#pragma unroll
            for (int g = 0; g < 4; g++) {
              bf16x4 pk;
#pragma unroll
              for (int i = 0; i < 4; i++) pk[i] = (bf16)fast_sigmoid(acc[4 * g + i]);
              *(bf16x4*)(Vnn + (size_t)(b * 128 + 32 * rt + la) * 1024 +
                         q0 + 32 * tt + 8 * g + 4 * hi) = pk;
            }
          }
        }
      }
    }
  } else {
    const int hs = wv & 1, nq = wv >> 1;
    float* outf = (float*)outp;
    bf16x8 wA[8];
#pragma unroll
    for (int ks = 0; ks < 8; ks++)
      wA[ks] = *(const bf16x8*)(Wo + (size_t)(la + 32 * hs) * 128 + hi * 8 + ks * 16);
#pragma unroll
    for (int t = 0; t < 2; t++) {
      const int ns4 = nq + 2 * t;
      f32x16 acc = ZERO16;
#pragma unroll
      for (int ks = 0; ks < 8; ks++) {
        bf16x8 oB = *(const bf16x8*)&O_lds[(size_t)(32 * ns4 + la) * 136 +
                                           hi * 8 + ks * 16];
        acc = MFMA32(wA[ks], oB, acc);
      }
#pragma unroll
      for (int g = 0; g < 4; g++) {
#pragma unroll
        for (int i = 0; i < 4; i++) {
          int h = 32 * hs + 8 * g + 4 * hi + i;
          float xv = acc[4 * g + i];
          outf[(size_t)(b * 64 + h) * 1024 + q0 + 32 * ns4 + la] =
              xv * fast_sigmoid(xv);
        }
      }
    }
  }
}

// ---------------- transpose x (fallback path) ------------------------------
__global__ __launch_bounds__(256) void xpose_kernel(const float* __restrict__ x,
                                                    bf16* __restrict__ xT) {
  __shared__ float tile[64][65];
  const int blk = blockIdx.x;
  const int b = blk >> 4;
  const int n0 = (blk & 15) * 64;
  const int tid = threadIdx.x;
  {
    const int nl = tid & 63, dbase = (tid >> 6) * 16;
#pragma unroll
    for (int i = 0; i < 16; i++) {
      int d = dbase + i;
      tile[d][nl] = x[(size_t)(b * 64 + d) * 1024 + n0 + nl];
    }
  }
  __syncthreads();
  {
    const int dl = (tid & 31) * 2, nb = (tid >> 5) * 8;
#pragma unroll
    for (int i = 0; i < 8; i++) {
      int n = nb + i;
      bf16x2 pr = {(bf16)tile[dl][n], (bf16)tile[dl + 1][n]};
      *(bf16x2*)(xT + (size_t)(b * 1024 + n0 + n) * 64 + dl) = pr;
    }
  }
}

// ---------------- host launch ----------------
extern "C" void kernel_launch(void* const* d_in, const int* in_sizes, int n_in,
                              void* d_out, int out_size, void* d_ws, size_t ws_size,
                              hipStream_t stream) {
  const float* x = (const float*)d_in[0];
  const int* L = (const int*)d_in[1];
  const float* wq0 = (const float*)d_in[2];
  const float* wqr = (const float*)d_in[3];
  const float* wk0 = (const float*)d_in[4];
  const float* wkr = (const float*)d_in[5];
  const float* wv0 = (const float*)d_in[6];
  const float* wvr = (const float*)d_in[7];
  const float* wor = (const float*)d_in[8];
  const float* wo_last = (const float*)d_in[9];

  char* ws = (char*)d_ws;
  float* scale_inv = (float*)(ws + 0);
  float* biasv = (float*)(ws + 1024);
  bf16* wbf = (bf16*)(ws + 4096);
  bf16* xT = (bf16*)(ws + 335872);
  bf16* inpT = (bf16*)(ws + 8724480);
  bf16* KtA = (bf16*)(ws + 25501696);
  bf16* VnA = (bf16*)(ws + 42278912);
  bf16* KtB = (bf16*)(ws + 59056128);
  bf16* VnB = (bf16*)(ws + 75833344);
  // bf16 weight offsets: wq0@0 wqr@8192 wk0@40960 wkr@49152 wv0@81920
  //                      wvr@90112 wor@122880 wo_last@155648

  prep_kernel<<<128, 256, 0, stream>>>(L, wq0, wqr, wk0, wkr, wv0, wvr, wor,
                                       wo_last, scale_inv, biasv, wbf);

  if (ws_size >= 92610560) {
    xk0_kernel<<<1024, 256, 0, stream>>>(x, wbf + 40960, wbf + 81920, xT, KtA, VnA);
    flash_kernel<64><<<512, 256, 0, stream>>>(
        xT, wbf + 0, KtA, VnA, scale_inv, biasv, L, wbf + 122880, (void*)inpT, 0,
        wbf + 49152, wbf + 90112, KtB, VnB, 1);
    flash_kernel<128><<<512, 256, 0, stream>>>(
        inpT, wbf + 8192, KtB, VnB, scale_inv, biasv, L, wbf + 139264,
        (void*)inpT, 0, wbf + 65536, wbf + 106496, KtA, VnA, 1);
    flash_kernel<128><<<512, 256, 0, stream>>>(
        inpT, wbf + 24576, KtA, VnA, scale_inv, biasv, L, wbf + 155648, d_out, 1,
        nullptr, nullptr, nullptr, nullptr, 0);
  } else if (ws_size >= 59056128) {
    xpose_kernel<<<1024, 256, 0, stream>>>(x, xT);
    for (int l = 0; l < 3; l++) {
      const bf16* Wq = (l == 0) ? wbf + 0 : wbf + 8192 + (size_t)(l - 1) * 16384;
      const bf16* Wk = (l == 0) ? wbf + 40960 : wbf + 49152 + (size_t)(l - 1) * 16384;
      const bf16* Wv = (l == 0) ? wbf + 81920 : wbf + 90112 + (size_t)(l - 1) * 16384;
      const bf16* Wo = (l < 2) ? wbf + 122880 + (size_t)l * 16384 : wbf + 155648;
      void* outp = (l < 2) ? (void*)inpT : (void*)d_out;
      if (l == 0) {
        kv_kernel<64><<<1024, 256, 0, stream>>>(xT, Wk, Wv, KtA, VnA);
        flash_kernel<64><<<512, 256, 0, stream>>>(xT, Wq, KtA, VnA, scale_inv,
                                                  biasv, L, Wo, outp, 0,
                                                  nullptr, nullptr, nullptr,
                                                  nullptr, 0);
      } else {
        kv_kernel<128><<<1024, 256, 0, stream>>>(inpT, Wk, Wv, KtA, VnA);
        flash_kernel<128><<<512, 256, 0, stream>>>(inpT, Wq, KtA, VnA, scale_inv,
                                                   biasv, L, Wo, outp,
                                                   (l == 2) ? 1 : 0, nullptr,
                                                   nullptr, nullptr, nullptr, 0);
      }
    }
  }
}